// Round 3
// baseline (867.176 us; speedup 1.0000x reference)
//
#include <hip/hip_runtime.h>
#include <math.h>

#define Nn 2048
#define Dd 128
#define Ee 8
#define NIT 8
#define KT (Nn*Ee)   // 16384

typedef __bf16 bf16;
typedef __attribute__((ext_vector_type(8))) __bf16 bf16x8;
typedef __attribute__((ext_vector_type(4))) float f32x4;

__device__ __forceinline__ f32x4 mfma16(bf16x8 a, bf16x8 b, f32x4 c){
    return __builtin_amdgcn_mfma_f32_16x16x32_bf16(a, b, c, 0, 0, 0);
}

// ---------------------------------------------------------------------------
// Prep (fp32 inputs): h fp32 master + bf16 copy; bf16-transposed weights.
// WmT[e][h][d], WiT[j][d], WhT[j][d], ArT[h][d]
// ---------------------------------------------------------------------------
__global__ __launch_bounds__(256) void k_prep(
    const float* __restrict__ node, const float* __restrict__ Wmsg,
    const float* __restrict__ Wi,   const float* __restrict__ Wh,
    const float* __restrict__ Ar,
    float* __restrict__ h32, bf16* __restrict__ hb,
    bf16* __restrict__ WmT, bf16* __restrict__ WiT, bf16* __restrict__ WhT,
    bf16* __restrict__ ArT)
{
    int tid = blockIdx.x*256 + threadIdx.x;
    int stride = gridDim.x*256;
    for (int i = tid; i < Nn*Dd; i += stride){
        float v = node[i]; h32[i] = v; hb[i] = (bf16)v;
    }
    for (int i = tid; i < Ee*Dd*Dd; i += stride){
        int e = i >> 14; int r = i & 16383; int h = r >> 7; int d = r & 127;
        WmT[i] = (bf16)Wmsg[e*Dd*Dd + d*Dd + h];
    }
    for (int i = tid; i < 384*Dd; i += stride){
        int j = i >> 7; int d = i & 127;
        WiT[i] = (bf16)Wi[d*384 + j];
        WhT[i] = (bf16)Wh[d*384 + j];
    }
    for (int i = tid; i < Dd*Dd; i += stride){
        int h = i >> 7; int d = i & 127;
        ArT[i] = (bf16)Ar[d*Dd + h];
    }
}

// ---------------------------------------------------------------------------
// Per-edge transform: Pt[h][s*8+e] = (hb @ W_e)[s][h]  (bf16 out)
// Also (e==0 blocks) init messages[t][h] = b_msg[h] for the atomic split-K.
// ---------------------------------------------------------------------------
__global__ __launch_bounds__(256) void k_per_edge(
    const bf16* __restrict__ hb, const bf16* __restrict__ WmT,
    const float* __restrict__ bmsg, bf16* __restrict__ Pt, float* __restrict__ msg)
{
    __shared__ bf16 Blds[Dd][Dd+8];
    const int e  = blockIdx.y;
    const int s0 = blockIdx.x * 64;
    const int tid = threadIdx.x;
    const bf16* src = WmT + e*Dd*Dd;
    for (int i = 0; i < 8; i++){
        int idx = tid + i*256; int row = idx >> 4, c = idx & 15;
        *(bf16x8*)&Blds[row][c*8] = *(const bf16x8*)&src[row*Dd + c*8];
    }
    __syncthreads();
    const int lane = tid & 63, wave = tid >> 6;
    const int quad = lane >> 4, l16 = lane & 15;
    const int srow = s0 + wave*16 + l16;
    f32x4 acc[8];
    for (int nt = 0; nt < 8; nt++) acc[nt] = (f32x4){0.f,0.f,0.f,0.f};
    for (int kk = 0; kk < 4; kk++){
        int k0 = kk*32 + quad*8;
        bf16x8 a = *(const bf16x8*)&hb[srow*Dd + k0];
        for (int nt = 0; nt < 8; nt++){
            bf16x8 b = *(const bf16x8*)&Blds[nt*16 + l16][k0];
            acc[nt] = mfma16(a, b, acc[nt]);
        }
    }
    for (int nt = 0; nt < 8; nt++){
        int h = nt*16 + l16;
        for (int r = 0; r < 4; r++){
            int s = s0 + wave*16 + quad*4 + r;
            Pt[h*KT + s*Ee + e] = (bf16)acc[nt][r];
        }
    }
    if (e == 0){
        for (int i = tid; i < 64*Dd; i += 256){
            int rr = i >> 7, h = i & 127;
            msg[(s0+rr)*Dd + h] = bmsg[h];
        }
    }
}

// ---------------------------------------------------------------------------
// messages[t][h] += sum_k edge-as-A[t][k] * Pt[h][k],  k = s*8+e
// A direct from global fp32 edge (native layout, L3-resident), converted to
// bf16 in-register. B LDS-staged, split-K=16 atomic.
// ---------------------------------------------------------------------------
__global__ __launch_bounds__(256) void k_msg_gemm(
    const float* __restrict__ edge, const bf16* __restrict__ Pt,
    float* __restrict__ msg)
{
    __shared__ bf16 Blds[Dd][Dd+8];
    const int t0 = blockIdx.x * 64;
    const int kbase = blockIdx.y * (KT/16);
    const int tid = threadIdx.x;
    const int lane = tid & 63, wave = tid >> 6;
    const int quad = lane >> 4, l16 = lane & 15;
    const int trow = t0 + wave*16 + l16;
    f32x4 acc[8];
    for (int nt = 0; nt < 8; nt++) acc[nt] = (f32x4){0.f,0.f,0.f,0.f};
    for (int ch = 0; ch < 8; ch++){
        int kc = kbase + ch*128;
        for (int i = 0; i < 8; i++){
            int idx = tid + i*256; int row = idx >> 4, c = idx & 15;
            *(bf16x8*)&Blds[row][c*8] = *(const bf16x8*)&Pt[row*KT + kc + c*8];
        }
        __syncthreads();
        int sb = kc >> 3;
        for (int kk = 0; kk < 4; kk++){
            int s = sb + kk*4 + quad;
            const float* ep = &edge[(size_t)s*(Nn*Ee) + trow*Ee];
            f32x4 e0 = *(const f32x4*)ep;
            f32x4 e1 = *(const f32x4*)(ep + 4);
            bf16x8 a;
            for (int j = 0; j < 4; j++){ a[j] = (bf16)e0[j]; a[j+4] = (bf16)e1[j]; }
            int kl = kk*32 + quad*8;
            for (int nt = 0; nt < 8; nt++){
                bf16x8 b = *(const bf16x8*)&Blds[nt*16 + l16][kl];
                acc[nt] = mfma16(a, b, acc[nt]);
            }
        }
        __syncthreads();
    }
    for (int nt = 0; nt < 8; nt++){
        int h = nt*16 + l16;
        for (int r = 0; r < 4; r++){
            int trw = t0 + wave*16 + quad*4 + r;
            atomicAdd(&msg[trw*Dd + h], acc[nt][r]);
        }
    }
}

// ---------------------------------------------------------------------------
// GRU: Gi = msg@Wi, Gh = h@Wh, gates, h update. fp32 master + bf16 copy.
// ---------------------------------------------------------------------------
__global__ __launch_bounds__(256) void k_gru(
    const float* __restrict__ msg, const bf16* __restrict__ WiT,
    const bf16* __restrict__ WhT, const float* __restrict__ bgru,
    float* __restrict__ h32, bf16* __restrict__ hb)
{
    __shared__ __align__(16) bf16 stage[384][40];   // 30720 B
    __shared__ float Gs[16][384];                    // 24576 B
    __shared__ float Ghn[16][128];                   //  8192 B

    const int t0 = blockIdx.x * 16;
    const int tid = threadIdx.x;
    const int lane = tid & 63, wave = tid >> 6;
    const int quad = lane >> 4, l16 = lane & 15;

    f32x4 accA[6], accB[6];
    for (int i = 0; i < 6; i++){ accA[i] = (f32x4){0.f,0.f,0.f,0.f}; accB[i] = (f32x4){0.f,0.f,0.f,0.f}; }

    for (int mat = 0; mat < 2; mat++){
        const bf16* WT = mat == 0 ? WiT : WhT;
        for (int kc = 0; kc < 4; kc++){
            for (int i = 0; i < 6; i++){
                int idx = tid + i*256; int row = idx >> 2, c = idx & 3;
                *(bf16x8*)&stage[row][c*8] = *(const bf16x8*)&WT[row*Dd + kc*32 + c*8];
            }
            __syncthreads();
            int k0 = kc*32 + quad*8;
            bf16x8 a;
            if (mat == 0){
                const float* mrow = &msg[(t0 + l16)*Dd + k0];
                for (int j = 0; j < 8; j++) a[j] = (bf16)mrow[j];
            } else {
                a = *(const bf16x8*)&hb[(t0 + l16)*Dd + k0];
            }
            for (int tt = 0; tt < 6; tt++){
                int T = wave*6 + tt;
                bf16x8 b = *(const bf16x8*)&stage[T*16 + l16][quad*8];
                if (mat == 0 || T < 16) accA[tt] = mfma16(a, b, accA[tt]);
                else                    accB[tt] = mfma16(a, b, accB[tt]);
            }
            __syncthreads();
        }
    }
    for (int tt = 0; tt < 6; tt++){
        int T = wave*6 + tt;
        int j = T*16 + l16;
        for (int r = 0; r < 4; r++){
            int m = quad*4 + r;
            Gs[m][j] = accA[tt][r];
            if (T >= 16) Ghn[m][j - 256] = accB[tt][r];
        }
    }
    __syncthreads();
    for (int i = 0; i < 8; i++){
        int cell = tid + i*256;
        int m = cell >> 7, jd = cell & 127;
        int t = t0 + m;
        float xr = Gs[m][jd]       + bgru[jd];
        float xz = Gs[m][jd + 128] + bgru[jd + 128];
        float xn = Gs[m][jd + 256] + bgru[jd + 256];
        xr = fminf(fmaxf(xr, -30.f), 30.f);
        xz = fminf(fmaxf(xz, -30.f), 30.f);
        float r = 1.f / (1.f + expf(-xr));
        float z = 1.f / (1.f + expf(-xz));
        float targ = xn + r * Ghn[m][jd];
        targ = fminf(fmaxf(targ, -15.f), 15.f);
        float n = tanhf(targ);
        float ho = h32[t*Dd + jd];
        float hnew = (1.f - z) * n + z * ho;
        h32[t*Dd + jd] = hnew;
        hb [t*Dd + jd] = (bf16)hnew;
    }
}

// ---------------------------------------------------------------------------
// Readout 1: t1 = hb @ A_readout  (via ArT[h][d]), bf16 out (internal)
// ---------------------------------------------------------------------------
__global__ __launch_bounds__(256) void k_read1(
    const bf16* __restrict__ hb, const bf16* __restrict__ ArT, bf16* __restrict__ t1)
{
    __shared__ bf16 Blds[Dd][Dd+8];
    const int s0 = blockIdx.x * 64;
    const int tid = threadIdx.x;
    for (int i = 0; i < 8; i++){
        int idx = tid + i*256; int row = idx >> 4, c = idx & 15;
        *(bf16x8*)&Blds[row][c*8] = *(const bf16x8*)&ArT[row*Dd + c*8];
    }
    __syncthreads();
    const int lane = tid & 63, wave = tid >> 6;
    const int quad = lane >> 4, l16 = lane & 15;
    const int srow = s0 + wave*16 + l16;
    f32x4 acc[8];
    for (int nt = 0; nt < 8; nt++) acc[nt] = (f32x4){0.f,0.f,0.f,0.f};
    for (int kk = 0; kk < 4; kk++){
        int k0 = kk*32 + quad*8;
        bf16x8 a = *(const bf16x8*)&hb[srow*Dd + k0];
        for (int nt = 0; nt < 8; nt++){
            bf16x8 b = *(const bf16x8*)&Blds[nt*16 + l16][k0];
            acc[nt] = mfma16(a, b, acc[nt]);
        }
    }
    for (int nt = 0; nt < 8; nt++){
        int h = nt*16 + l16;
        for (int r = 0; r < 4; r++){
            int s = s0 + wave*16 + quad*4 + r;
            t1[s*Dd + h] = (bf16)acc[nt][r];
        }
    }
}

// ---------------------------------------------------------------------------
// Readout 2: logits[i][j] = sum_d t1[i][d]*hb[j][d], fp32 out
// ---------------------------------------------------------------------------
__global__ __launch_bounds__(256) void k_read2(
    const bf16* __restrict__ t1, const bf16* __restrict__ hb, float* __restrict__ out)
{
    const int i0 = blockIdx.x * 64, j0 = blockIdx.y * 128;
    const int tid = threadIdx.x;
    const int lane = tid & 63, wave = tid >> 6;
    const int quad = lane >> 4, l16 = lane & 15;
    const int irow = i0 + wave*16 + l16;
    f32x4 acc[8];
    for (int nt = 0; nt < 8; nt++) acc[nt] = (f32x4){0.f,0.f,0.f,0.f};
    for (int kk = 0; kk < 4; kk++){
        int k0 = kk*32 + quad*8;
        bf16x8 a = *(const bf16x8*)&t1[irow*Dd + k0];
        for (int nt = 0; nt < 8; nt++){
            int j = j0 + nt*16 + l16;
            bf16x8 b = *(const bf16x8*)&hb[j*Dd + k0];
            acc[nt] = mfma16(a, b, acc[nt]);
        }
    }
    for (int nt = 0; nt < 8; nt++){
        int j = j0 + nt*16 + l16;
        for (int r = 0; r < 4; r++){
            int irw = i0 + wave*16 + quad*4 + r;
            out[(size_t)irw*Nn + j] = acc[nt][r];
        }
    }
}

// ---------------------------------------------------------------------------
extern "C" void kernel_launch(void* const* d_in, const int* in_sizes, int n_in,
                              void* d_out, int out_size, void* d_ws, size_t ws_size,
                              hipStream_t stream)
{
    const float* node = (const float*)d_in[0];
    const float* edge = (const float*)d_in[1];
    const float* Wmsg = (const float*)d_in[2];
    const float* bmsg = (const float*)d_in[3];
    const float* Wi   = (const float*)d_in[4];
    const float* Wh   = (const float*)d_in[5];
    const float* bgru = (const float*)d_in[6];
    const float* Ar   = (const float*)d_in[7];
    float* out = (float*)d_out;

    char* ws = (char*)d_ws;
    bf16*  Pt  = (bf16*)ws;              ws += (size_t)Dd*KT*2;
    float* msg = (float*)ws;             ws += (size_t)Nn*Dd*4;
    float* h32 = (float*)ws;             ws += (size_t)Nn*Dd*4;
    bf16*  hb  = (bf16*)ws;              ws += (size_t)Nn*Dd*2;
    bf16*  WmT = (bf16*)ws;              ws += (size_t)Ee*Dd*Dd*2;
    bf16*  WiT = (bf16*)ws;              ws += (size_t)384*Dd*2;
    bf16*  WhT = (bf16*)ws;              ws += (size_t)384*Dd*2;
    bf16*  ArT = (bf16*)ws;              ws += (size_t)Dd*Dd*2;
    bf16*  t1  = (bf16*)ws;              ws += (size_t)Nn*Dd*2;

    k_prep<<<dim3(256), 256, 0, stream>>>(node, Wmsg, Wi, Wh, Ar,
                                          h32, hb, WmT, WiT, WhT, ArT);
    for (int it = 0; it < NIT; it++){
        k_per_edge<<<dim3(32, 8),  256, 0, stream>>>(hb, WmT, bmsg, Pt, msg);
        k_msg_gemm<<<dim3(32, 16), 256, 0, stream>>>(edge, Pt, msg);
        k_gru     <<<dim3(128),    256, 0, stream>>>(msg, WiT, WhT, bgru, h32, hb);
    }
    k_read1<<<dim3(32),     256, 0, stream>>>(hb, ArT, t1);
    k_read2<<<dim3(32, 16), 256, 0, stream>>>(t1, hb, out);
}

// Round 4
// 736.749 us; speedup vs baseline: 1.1770x; 1.1770x over previous
//
#include <hip/hip_runtime.h>
#include <math.h>

#define Nn 2048
#define Dd 128
#define Ee 8
#define NIT 8
#define KT (Nn*Ee)   // 16384
#define KSPLIT 16

typedef __bf16 bf16;
typedef __attribute__((ext_vector_type(8))) __bf16 bf16x8;
typedef __attribute__((ext_vector_type(4))) float f32x4;

__device__ __forceinline__ f32x4 mfma16(bf16x8 a, bf16x8 b, f32x4 c){
    return __builtin_amdgcn_mfma_f32_16x16x32_bf16(a, b, c, 0, 0, 0);
}

// ---------------------------------------------------------------------------
// Prep (fp32 inputs): h fp32 master + bf16 copy; bf16-transposed weights.
// WmT[e][h][d], WiT[j][d], WhT[j][d], ArT[h][d]
// ---------------------------------------------------------------------------
__global__ __launch_bounds__(256) void k_prep(
    const float* __restrict__ node, const float* __restrict__ Wmsg,
    const float* __restrict__ Wi,   const float* __restrict__ Wh,
    const float* __restrict__ Ar,
    float* __restrict__ h32, bf16* __restrict__ hb,
    bf16* __restrict__ WmT, bf16* __restrict__ WiT, bf16* __restrict__ WhT,
    bf16* __restrict__ ArT)
{
    int tid = blockIdx.x*256 + threadIdx.x;
    int stride = gridDim.x*256;
    for (int i = tid; i < Nn*Dd; i += stride){
        float v = node[i]; h32[i] = v; hb[i] = (bf16)v;
    }
    for (int i = tid; i < Ee*Dd*Dd; i += stride){
        int e = i >> 14; int r = i & 16383; int h = r >> 7; int d = r & 127;
        WmT[i] = (bf16)Wmsg[e*Dd*Dd + d*Dd + h];
    }
    for (int i = tid; i < 384*Dd; i += stride){
        int j = i >> 7; int d = i & 127;
        WiT[i] = (bf16)Wi[d*384 + j];
        WhT[i] = (bf16)Wh[d*384 + j];
    }
    for (int i = tid; i < Dd*Dd; i += stride){
        int h = i >> 7; int d = i & 127;
        ArT[i] = (bf16)Ar[d*Dd + h];
    }
}

// ---------------------------------------------------------------------------
// Edge fp32 -> bf16 once. 33.5M elements; memory-bound (~30 us one-time).
// ---------------------------------------------------------------------------
__global__ __launch_bounds__(256) void k_prep_edge(
    const float* __restrict__ edge, bf16* __restrict__ edge_bf)
{
    const size_t total = (size_t)Nn*Nn*Ee;          // 33,554,432
    size_t base = ((size_t)blockIdx.x*256 + threadIdx.x)*8;
    size_t stride = (size_t)gridDim.x*256*8;
    for (size_t i = base; i < total; i += stride){
        f32x4 v0 = *(const f32x4*)&edge[i];
        f32x4 v1 = *(const f32x4*)&edge[i+4];
        bf16x8 o;
        for (int j = 0; j < 4; j++){ o[j] = (bf16)v0[j]; o[j+4] = (bf16)v1[j]; }
        *(bf16x8*)&edge_bf[i] = o;
    }
}

// ---------------------------------------------------------------------------
// Per-edge transform, ALL 8 edge types per block:
//   Pt[h][s*8+e] = (hb @ W_e)[s][h]   -> 16B bf16x8 stores (8 e contiguous)
// grid (32 s-tiles of 64, 8 h-tiles of 16), block 256 (4 waves x 16 s rows)
// ---------------------------------------------------------------------------
__global__ __launch_bounds__(256) void k_per_edge(
    const bf16* __restrict__ hb, const bf16* __restrict__ WmT,
    bf16* __restrict__ Pt)
{
    __shared__ bf16 Blds[Ee][16][Dd+8];             // 34,816 B
    const int s0 = blockIdx.x * 64;
    const int h0 = blockIdx.y * 16;
    const int tid = threadIdx.x;
    // stage all 8 W_e^T h-strips: 8 e x 16 h x 128 d
    for (int i = 0; i < 8; i++){
        int idx = tid + i*256;                      // 2048 chunks of 8
        int e = idx >> 8, row = (idx >> 4) & 15, c = idx & 15;
        *(bf16x8*)&Blds[e][row][c*8] =
            *(const bf16x8*)&WmT[e*Dd*Dd + (h0+row)*Dd + c*8];
    }
    __syncthreads();
    const int lane = tid & 63, wave = tid >> 6;
    const int quad = lane >> 4, l16 = lane & 15;
    const int srow = s0 + wave*16 + l16;
    f32x4 acc[Ee];
    for (int e = 0; e < Ee; e++) acc[e] = (f32x4){0.f,0.f,0.f,0.f};
    for (int kk = 0; kk < 4; kk++){
        int k0 = kk*32 + quad*8;
        bf16x8 a = *(const bf16x8*)&hb[srow*Dd + k0];
        for (int e = 0; e < Ee; e++){
            bf16x8 b = *(const bf16x8*)&Blds[e][l16][k0];
            acc[e] = mfma16(a, b, acc[e]);
        }
    }
    // lane (quad,r): s = s0+wave*16+quad*4+r, h = h0+l16; 8 e's contiguous
    const int h = h0 + l16;
    for (int r = 0; r < 4; r++){
        int s = s0 + wave*16 + quad*4 + r;
        bf16x8 po;
        for (int e = 0; e < Ee; e++) po[e] = (bf16)acc[e][r];
        *(bf16x8*)&Pt[(size_t)h*KT + s*Ee] = po;
    }
}

// ---------------------------------------------------------------------------
// msgP[ks][t][h] = sum_{k in split} edgeA[t][k] * Pt[h][k],  k = s*8+e
// A direct bf16 from edge_bf (native layout), B LDS-staged. Plain stores
// (no atomics); reduction over ks folded into k_gru.
// grid (32 t-tiles, KSPLIT), block 256
// ---------------------------------------------------------------------------
__global__ __launch_bounds__(256) void k_msg_gemm(
    const bf16* __restrict__ edge_bf, const bf16* __restrict__ Pt,
    float* __restrict__ msgP)
{
    __shared__ bf16 Blds[Dd][Dd+8];
    const int t0 = blockIdx.x * 64;
    const int kbase = blockIdx.y * (KT/KSPLIT);     // 1024 k = 128 s
    const int tid = threadIdx.x;
    const int lane = tid & 63, wave = tid >> 6;
    const int quad = lane >> 4, l16 = lane & 15;
    const int trow = t0 + wave*16 + l16;
    f32x4 acc[8];
    for (int nt = 0; nt < 8; nt++) acc[nt] = (f32x4){0.f,0.f,0.f,0.f};
    for (int ch = 0; ch < 8; ch++){
        int kc = kbase + ch*128;
        for (int i = 0; i < 8; i++){
            int idx = tid + i*256; int row = idx >> 4, c = idx & 15;
            *(bf16x8*)&Blds[row][c*8] = *(const bf16x8*)&Pt[(size_t)row*KT + kc + c*8];
        }
        __syncthreads();
        int sb = kc >> 3;
        for (int kk = 0; kk < 4; kk++){
            int s = sb + kk*4 + quad;
            bf16x8 a = *(const bf16x8*)&edge_bf[(size_t)s*(Nn*Ee) + trow*Ee];
            int kl = kk*32 + quad*8;
            for (int nt = 0; nt < 8; nt++){
                bf16x8 b = *(const bf16x8*)&Blds[nt*16 + l16][kl];
                acc[nt] = mfma16(a, b, acc[nt]);
            }
        }
        __syncthreads();
    }
    float* dst = msgP + (size_t)blockIdx.y*Nn*Dd;
    for (int nt = 0; nt < 8; nt++){
        int h = nt*16 + l16;
        for (int r = 0; r < 4; r++){
            int trw = t0 + wave*16 + quad*4 + r;
            dst[(size_t)trw*Dd + h] = acc[nt][r];
        }
    }
}

// ---------------------------------------------------------------------------
// GRU: messages = sum_ks msgP + b_msg (folded into A build);
// Gi = msg@Wi, Gh = h@Wh, gates, h update. fp32 master + bf16 copy.
// ---------------------------------------------------------------------------
__global__ __launch_bounds__(256) void k_gru(
    const float* __restrict__ msgP, const bf16* __restrict__ WiT,
    const bf16* __restrict__ WhT, const float* __restrict__ bmsg,
    const float* __restrict__ bgru,
    float* __restrict__ h32, bf16* __restrict__ hb)
{
    __shared__ __align__(16) bf16 stage[384][40];   // 30720 B
    __shared__ float Gs[16][384];                    // 24576 B
    __shared__ float Ghn[16][128];                   //  8192 B

    const int t0 = blockIdx.x * 16;
    const int tid = threadIdx.x;
    const int lane = tid & 63, wave = tid >> 6;
    const int quad = lane >> 4, l16 = lane & 15;

    f32x4 accA[6], accB[6];
    for (int i = 0; i < 6; i++){ accA[i] = (f32x4){0.f,0.f,0.f,0.f}; accB[i] = (f32x4){0.f,0.f,0.f,0.f}; }

    for (int mat = 0; mat < 2; mat++){
        const bf16* WT = mat == 0 ? WiT : WhT;
        for (int kc = 0; kc < 4; kc++){
            for (int i = 0; i < 6; i++){
                int idx = tid + i*256; int row = idx >> 2, c = idx & 3;
                *(bf16x8*)&stage[row][c*8] = *(const bf16x8*)&WT[row*Dd + kc*32 + c*8];
            }
            __syncthreads();
            int k0 = kc*32 + quad*8;
            bf16x8 a;
            if (mat == 0){
                const float* mp = &msgP[(size_t)(t0 + l16)*Dd + k0];
                f32x4 s0 = *(const f32x4*)&bmsg[k0];
                f32x4 s1 = *(const f32x4*)&bmsg[k0+4];
                for (int p = 0; p < KSPLIT; p++){
                    s0 += *(const f32x4*)&mp[(size_t)p*Nn*Dd];
                    s1 += *(const f32x4*)&mp[(size_t)p*Nn*Dd + 4];
                }
                for (int j = 0; j < 4; j++){ a[j] = (bf16)s0[j]; a[j+4] = (bf16)s1[j]; }
            } else {
                a = *(const bf16x8*)&hb[(t0 + l16)*Dd + k0];
            }
            for (int tt = 0; tt < 6; tt++){
                int T = wave*6 + tt;
                bf16x8 b = *(const bf16x8*)&stage[T*16 + l16][quad*8];
                if (mat == 0 || T < 16) accA[tt] = mfma16(a, b, accA[tt]);
                else                    accB[tt] = mfma16(a, b, accB[tt]);
            }
            __syncthreads();
        }
    }
    for (int tt = 0; tt < 6; tt++){
        int T = wave*6 + tt;
        int j = T*16 + l16;
        for (int r = 0; r < 4; r++){
            int m = quad*4 + r;
            Gs[m][j] = accA[tt][r];
            if (T >= 16) Ghn[m][j - 256] = accB[tt][r];
        }
    }
    __syncthreads();
    for (int i = 0; i < 8; i++){
        int cell = tid + i*256;
        int m = cell >> 7, jd = cell & 127;
        int t = t0 + m;
        float xr = Gs[m][jd]       + bgru[jd];
        float xz = Gs[m][jd + 128] + bgru[jd + 128];
        float xn = Gs[m][jd + 256] + bgru[jd + 256];
        float r = 1.f / (1.f + expf(-xr));
        float z = 1.f / (1.f + expf(-xz));
        float n = tanhf(xn + r * Ghn[m][jd]);
        float ho = h32[t*Dd + jd];
        float hnew = (1.f - z) * n + z * ho;
        h32[t*Dd + jd] = hnew;
        hb [t*Dd + jd] = (bf16)hnew;
    }
}

// ---------------------------------------------------------------------------
// Readout 1: t1 = hb @ A_readout  (via ArT[h][d]), bf16 out (internal)
// ---------------------------------------------------------------------------
__global__ __launch_bounds__(256) void k_read1(
    const bf16* __restrict__ hb, const bf16* __restrict__ ArT, bf16* __restrict__ t1)
{
    __shared__ bf16 Blds[Dd][Dd+8];
    const int s0 = blockIdx.x * 64;
    const int tid = threadIdx.x;
    for (int i = 0; i < 8; i++){
        int idx = tid + i*256; int row = idx >> 4, c = idx & 15;
        *(bf16x8*)&Blds[row][c*8] = *(const bf16x8*)&ArT[row*Dd + c*8];
    }
    __syncthreads();
    const int lane = tid & 63, wave = tid >> 6;
    const int quad = lane >> 4, l16 = lane & 15;
    const int srow = s0 + wave*16 + l16;
    f32x4 acc[8];
    for (int nt = 0; nt < 8; nt++) acc[nt] = (f32x4){0.f,0.f,0.f,0.f};
    for (int kk = 0; kk < 4; kk++){
        int k0 = kk*32 + quad*8;
        bf16x8 a = *(const bf16x8*)&hb[srow*Dd + k0];
        for (int nt = 0; nt < 8; nt++){
            bf16x8 b = *(const bf16x8*)&Blds[nt*16 + l16][k0];
            acc[nt] = mfma16(a, b, acc[nt]);
        }
    }
    for (int nt = 0; nt < 8; nt++){
        int h = nt*16 + l16;
        for (int r = 0; r < 4; r++){
            int s = s0 + wave*16 + quad*4 + r;
            t1[s*Dd + h] = (bf16)acc[nt][r];
        }
    }
}

// ---------------------------------------------------------------------------
// Readout 2: logits[i][j] = sum_d t1[i][d]*hb[j][d], fp32 out
// ---------------------------------------------------------------------------
__global__ __launch_bounds__(256) void k_read2(
    const bf16* __restrict__ t1, const bf16* __restrict__ hb, float* __restrict__ out)
{
    const int i0 = blockIdx.x * 64, j0 = blockIdx.y * 128;
    const int tid = threadIdx.x;
    const int lane = tid & 63, wave = tid >> 6;
    const int quad = lane >> 4, l16 = lane & 15;
    const int irow = i0 + wave*16 + l16;
    f32x4 acc[8];
    for (int nt = 0; nt < 8; nt++) acc[nt] = (f32x4){0.f,0.f,0.f,0.f};
    for (int kk = 0; kk < 4; kk++){
        int k0 = kk*32 + quad*8;
        bf16x8 a = *(const bf16x8*)&t1[irow*Dd + k0];
        for (int nt = 0; nt < 8; nt++){
            int j = j0 + nt*16 + l16;
            bf16x8 b = *(const bf16x8*)&hb[j*Dd + k0];
            acc[nt] = mfma16(a, b, acc[nt]);
        }
    }
    for (int nt = 0; nt < 8; nt++){
        int j = j0 + nt*16 + l16;
        for (int r = 0; r < 4; r++){
            int irw = i0 + wave*16 + quad*4 + r;
            out[(size_t)irw*Nn + j] = acc[nt][r];
        }
    }
}

// ---------------------------------------------------------------------------
extern "C" void kernel_launch(void* const* d_in, const int* in_sizes, int n_in,
                              void* d_out, int out_size, void* d_ws, size_t ws_size,
                              hipStream_t stream)
{
    const float* node = (const float*)d_in[0];
    const float* edge = (const float*)d_in[1];
    const float* Wmsg = (const float*)d_in[2];
    const float* bmsg = (const float*)d_in[3];
    const float* Wi   = (const float*)d_in[4];
    const float* Wh   = (const float*)d_in[5];
    const float* bgru = (const float*)d_in[6];
    const float* Ar   = (const float*)d_in[7];
    float* out = (float*)d_out;

    char* ws = (char*)d_ws;
    bf16*  edge_bf = (bf16*)ws;          ws += (size_t)Nn*Nn*Ee*2;      // 64 MiB
    float* msgP = (float*)ws;            ws += (size_t)KSPLIT*Nn*Dd*4;  // 16 MiB
    bf16*  Pt  = (bf16*)ws;              ws += (size_t)Dd*KT*2;         //  4 MiB
    float* h32 = (float*)ws;             ws += (size_t)Nn*Dd*4;
    bf16*  hb  = (bf16*)ws;              ws += (size_t)Nn*Dd*2;
    bf16*  WmT = (bf16*)ws;              ws += (size_t)Ee*Dd*Dd*2;
    bf16*  WiT = (bf16*)ws;              ws += (size_t)384*Dd*2;
    bf16*  WhT = (bf16*)ws;              ws += (size_t)384*Dd*2;
    bf16*  ArT = (bf16*)ws;              ws += (size_t)Dd*Dd*2;
    bf16*  t1  = (bf16*)ws;              ws += (size_t)Nn*Dd*2;

    k_prep<<<dim3(256), 256, 0, stream>>>(node, Wmsg, Wi, Wh, Ar,
                                          h32, hb, WmT, WiT, WhT, ArT);
    k_prep_edge<<<dim3(4096), 256, 0, stream>>>(edge, edge_bf);
    for (int it = 0; it < NIT; it++){
        k_per_edge<<<dim3(32, 8),      256, 0, stream>>>(hb, WmT, Pt);
        k_msg_gemm<<<dim3(32, KSPLIT), 256, 0, stream>>>(edge_bf, Pt, msgP);
        k_gru     <<<dim3(128),        256, 0, stream>>>(msgP, WiT, WhT, bmsg, bgru, h32, hb);
    }
    k_read1<<<dim3(32),     256, 0, stream>>>(hb, ArT, t1);
    k_read2<<<dim3(32, 16), 256, 0, stream>>>(t1, hb, out);
}